// Round 9
// baseline (94.003 us; speedup 1.0000x reference)
//
#include <hip/hip_runtime.h>

// Chamfer loss: B=4, N=M=8192, D=3, fp32 in, scalar fp32 out.
// loss = mean_n min_m ||x_n-y_m||^2 + mean_m min_n ||...||^2 + lambda*bpp
//
// R8: 16x16x32 MFMA (4-reg accumulator) replaces 32x32x16 (16-reg).
// R7 evidence: VALU-busy 20us (4-5x the min-merge work) + occupancy 16%
// -> 4x16-reg accumulators spilled into AGPR budget + accvgpr moves
// before every fmin. With 4-reg accs the compiler keeps C/D in VGPRs.
// Math (bit-exact since R6): P = y2 - 2 x.y via split-bf16 in K:
//   k0-2: -2xhi*yhi  k3: 1*y2hi  k4-6: -2xlo*yhi  k7: 1*y2lo
//   k8-10: -2xhi*ylo k11-31: 0  (k16-31 fed by zero regs, lanes 32-63)
// A/B frag: row/col = lane&15, k-octet = lane>>4 (octets 2,3 = zero).
// C/D: col = lane&15, row = (lane>>4)*4 + q  [m89-verified family].
// Wave owns 128 rows (8 A frags) x 1024-col segment: 1 B load -> 8
// MFMAs; col-tile pairs merged via v_min3. 4096 waves (~4/SIMD).

typedef float f4v __attribute__((ext_vector_type(4)));
typedef short s8  __attribute__((ext_vector_type(8)));

#define NPTS   8192
#define NB     4
#define NPTOT  (NB * NPTS)        // 32768 points per cloud
#define NSEG   8                  // column-segment split (1024 cols each)
#define RBLK   128

__device__ __forceinline__ ushort f2bf(float f) {
    uint u = __float_as_uint(f);
    u += 0x7FFF + ((u >> 16) & 1);          // round-to-nearest-even
    return (ushort)(u >> 16);
}
__device__ __forceinline__ float bf2f(ushort h) {
    return __uint_as_float(((uint)h) << 16);
}
__device__ __forceinline__ uint pk(ushort lo, ushort hi) {
    return (uint)lo | ((uint)hi << 16);
}

// prep: per point (both clouds): split coords and ||p||^2 into bf16 hi/lo,
// store A-side and B-side records: 2 x uint4 = k-octets 0..7 and 8..15.
__global__ __launch_bounds__(256) void prep(
        const float* __restrict__ X, const float* __restrict__ Y,
        uint4* __restrict__ Arec, uint4* __restrict__ Brec) {
    int i = blockIdx.x * 256 + threadIdx.x;
    if (i >= 2 * NPTOT) return;
    const float* src = (i < NPTOT) ? X : Y;
    int p = i & (NPTOT - 1);
    float x0 = src[3*p], x1 = src[3*p+1], x2 = src[3*p+2];
    float n2 = __fmaf_rn(x0, x0, __fmaf_rn(x1, x1, x2 * x2));

    ushort h0 = f2bf(x0), h1 = f2bf(x1), h2 = f2bf(x2);
    ushort l0 = f2bf(x0 - bf2f(h0));
    ushort l1 = f2bf(x1 - bf2f(h1));
    ushort l2 = f2bf(x2 - bf2f(h2));
    ushort n2h = f2bf(n2);
    ushort n2l = f2bf(n2 - bf2f(n2h));
    ushort a0 = f2bf(-2.0f * bf2f(h0)), a1 = f2bf(-2.0f * bf2f(h1));
    ushort a2 = f2bf(-2.0f * bf2f(h2));
    ushort b0 = f2bf(-2.0f * bf2f(l0)), b1 = f2bf(-2.0f * bf2f(l1));
    ushort b2 = f2bf(-2.0f * bf2f(l2));
    const ushort ONE = 0x3F80;

    Arec[(size_t)i*2 + 0] = make_uint4(pk(a0,a1), pk(a2,ONE), pk(b0,b1), pk(b2,ONE));
    Arec[(size_t)i*2 + 1] = make_uint4(pk(a0,a1), pk(a2,0),   0,          0);
    Brec[(size_t)i*2 + 0] = make_uint4(pk(h0,h1), pk(h2,n2h), pk(h0,h1), pk(h2,n2l));
    Brec[(size_t)i*2 + 1] = make_uint4(pk(l0,l1), pk(l2,0),   0,          0);
}

#define LOADP(P, p)                                                         \
    if (lane < 32) {                                                        \
        P[0] = *(const s8*)(Bseg + ((size_t)(2*(p))   * 16 + col) * 2 + oct); \
        P[1] = *(const s8*)(Bseg + ((size_t)(2*(p)+1) * 16 + col) * 2 + oct); \
    } else { P[0] = zf; P[1] = zf; }

#define COMPP(P)                                                            \
    {                                                                       \
        f4v acc0[8], acc1[8];                                               \
        _Pragma("unroll")                                                   \
        for (int a = 0; a < 8; a++)                                         \
            acc0[a] = __builtin_amdgcn_mfma_f32_16x16x32_bf16(A[a], P[0], zero4, 0, 0, 0); \
        _Pragma("unroll")                                                   \
        for (int a = 0; a < 8; a++)                                         \
            acc1[a] = __builtin_amdgcn_mfma_f32_16x16x32_bf16(A[a], P[1], zero4, 0, 0, 0); \
        _Pragma("unroll")                                                   \
        for (int a = 0; a < 8; a++) {                                       \
            _Pragma("unroll")                                               \
            for (int q = 0; q < 4; q++)                                     \
                racc[a][q] = fminf(fminf(acc0[a][q], acc1[a][q]), racc[a][q]); \
        }                                                                   \
    }

__global__ __launch_bounds__(256) void mfma_pass(
        const uint4* __restrict__ Arec, const uint4* __restrict__ Brec,
        float* __restrict__ minsP) {
    // grid = 1024: pass(2) x batch(4) x rowblk(16) x seg(8)
    // block = 4 waves; wave owns 128 rows x one 1024-col segment
    int bid    = blockIdx.x;
    int pass   = bid >> 9;
    int r      = bid & 511;
    int b      = r >> 7;
    int rem    = r & 127;
    int rowblk = rem >> 3;
    int seg    = rem & 7;
    int lane   = threadIdx.x & 63;
    int wave   = threadIdx.x >> 6;
    int ca     = pass;              // A-cloud: 0=X,1=Y
    int cb     = 1 - pass;
    int rowbase = (rowblk * 4 + wave) * 128;
    int col    = lane & 15;
    int oct    = (lane >> 4) & 1;   // valid k-octet for lanes < 32

    const s8 zf = {0,0,0,0,0,0,0,0};
    const f4v zero4 = {0.f, 0.f, 0.f, 0.f};

    // 8 A fragments: rows [rowbase + a*16, +16)
    s8 A[8];
    {
        size_t pA = (size_t)ca * NPTOT + (size_t)b * NPTS + rowbase + col;
#pragma unroll
        for (int a = 0; a < 8; a++)
            A[a] = (lane < 32) ? *(const s8*)&Arec[(pA + a * 16) * 2 + oct] : zf;
    }

    // B segment base (1024 points)
    const uint4* Bseg = Brec + ((size_t)cb * NPTOT + (size_t)b * NPTS
                      + (size_t)seg * 1024) * 2;

    f4v racc[8];
#pragma unroll
    for (int a = 0; a < 8; a++)
#pragma unroll
        for (int q = 0; q < 4; q++) racc[a][q] = 3.0e38f;

    // 32 col-tile pairs, ping-pong prefetch
    s8 PA[2], PB[2];
    LOADP(PA, 0);
    for (int p = 0; p < 30; p += 2) {
        LOADP(PB, p + 1);
        COMPP(PA);
        LOADP(PA, p + 2);
        COMPP(PB);
    }
    LOADP(PB, 31);
    COMPP(PA);
    COMPP(PB);

    // row-min across 16 cols (lane bits 0-3), plain store per segment
    float* dst = minsP + ((size_t)seg * 2 + pass) * NPTOT + (size_t)b * NPTS
               + rowbase;
#pragma unroll
    for (int a = 0; a < 8; a++) {
#pragma unroll
        for (int q = 0; q < 4; q++) {
            float v = racc[a][q];
            v = fminf(v, __shfl_xor(v, 1, 64));
            v = fminf(v, __shfl_xor(v, 2, 64));
            v = fminf(v, __shfl_xor(v, 4, 64));
            v = fminf(v, __shfl_xor(v, 8, 64));
            if ((lane & 15) == 0)
                dst[a * 16 + (lane >> 4) * 4 + q] = v;
        }
    }
}

__global__ __launch_bounds__(256) void reduce1(
        const float* __restrict__ minsP,
        const float* __restrict__ X, const float* __restrict__ Y,
        float2* __restrict__ out2) {
    __shared__ float s1[256], s2[256];
    int t = threadIdx.x;
    int i = blockIdx.x * 256 + t;           // RBLK*256 == NPTOT exactly
    float mx = 3.0e38f, my = 3.0e38f;
#pragma unroll
    for (int s = 0; s < NSEG; s++) {
        mx = fminf(mx, minsP[((size_t)s * 2 + 0) * NPTOT + i]);
        my = fminf(my, minsP[((size_t)s * 2 + 1) * NPTOT + i]);
    }
    float a = X[3*i], bb = X[3*i+1], c = X[3*i+2];
    float sx = mx + __fmaf_rn(a, a, __fmaf_rn(bb, bb, c * c));
    float d = Y[3*i], e = Y[3*i+1], f = Y[3*i+2];
    float sy = my + __fmaf_rn(d, d, __fmaf_rn(e, e, f * f));
    s1[t] = sx; s2[t] = sy;
    __syncthreads();
    for (int s = 128; s > 0; s >>= 1) {
        if (t < s) { s1[t] += s1[t + s]; s2[t] += s2[t + s]; }
        __syncthreads();
    }
    if (t == 0) out2[blockIdx.x] = make_float2(s1[0], s2[0]);
}

__global__ __launch_bounds__(RBLK) void reduce2(
        const float2* __restrict__ p2,
        const float* __restrict__ bpp, const float* __restrict__ lam,
        float* __restrict__ out) {
    __shared__ float s[RBLK];
    int t = threadIdx.x;
    float2 p = p2[t];
    s[t] = p.x + p.y;
    __syncthreads();
    for (int h = RBLK / 2; h > 0; h >>= 1) {
        if (t < h) s[t] += s[t + h];
        __syncthreads();
    }
    if (t == 0) out[0] = s[0] * (1.0f / (float)NPTOT) + lam[0] * bpp[0];
}

extern "C" void kernel_launch(void* const* d_in, const int* in_sizes, int n_in,
                              void* d_out, int out_size, void* d_ws, size_t ws_size,
                              hipStream_t stream) {
    const float* X   = (const float*)d_in[0];   // pc_pred  [4,8192,3]
    const float* Y   = (const float*)d_in[1];   // pc_target[4,8192,3]
    const float* bpp = (const float*)d_in[2];
    const float* lam = (const float*)d_in[3];
    float* out = (float*)d_out;

    char* w = (char*)d_ws;
    float2* p2    = (float2*)w;                 w += 1024;
    float*  minsP = (float*)w;                  w += (size_t)NSEG * 2 * NPTOT * sizeof(float);
    uint4*  Arec  = (uint4*)w;                  w += (size_t)2 * NPTOT * 2 * sizeof(uint4);
    uint4*  Brec  = (uint4*)w;

    prep<<<(2 * NPTOT + 255) / 256, 256, 0, stream>>>(X, Y, Arec, Brec);
    mfma_pass<<<1024, 256, 0, stream>>>(Arec, Brec, minsP);
    reduce1<<<RBLK, 256, 0, stream>>>(minsP, X, Y, p2);
    reduce2<<<1, RBLK, 0, stream>>>(p2, bpp, lam, out);
}

// Round 10
// 47.585 us; speedup vs baseline: 1.9755x; 1.9755x over previous
//
#include <hip/hip_runtime.h>

// Chamfer loss: B=4, N=M=8192, D=3, fp32 in, scalar fp32 out.
// loss = mean_n min_m ||x_n-y_m||^2 + mean_m min_n ||...||^2 + lambda*bpp
//
// R9: back to 32x32x16 (R6-verified, best K-efficiency). Lesson from
// R7/R8: >32 simultaneous MFMA-result regs forces AGPR allocation +
// v_accvgpr_read before every fmin (VALU 20-27us vs 4us intended).
// Structure: wave owns 64 rows (A0,A1) x 2048-col segment; col-tiles in
// pairs, SEQUENCED so only 2 acc tiles (32 regs) are live at once:
//   acc0=mfma(A0,P0); acc1=mfma(A0,P1); racc0=min3(acc0,acc1,racc0)
//   acc0=mfma(A1,P0); acc1=mfma(A1,P1); racc1=min3(acc0,acc1,racc1)
// B reused 2x (256MB L1 traffic ~6.8us), min3 merge 3.4us, MFMA 1.7us.
// grid 1024 x 4 waves (~3 waves/SIMD at ~140 VGPR).
// Math (bit-exact since R6): P = y2 - 2 x.y via split-bf16 in K:
//   k0-2: -2xhi*yhi  k3: 1*y2hi  k4-6: -2xlo*yhi  k7: 1*y2lo
//   k8-10: -2xhi*ylo k11-15: 0
// A/B frag: row/col = lane&31, k-octet = lane>>5.
// C/D: col = lane&31, row = (q&3)+8*(q>>2)+4*(lane>>5).

typedef float  f16v __attribute__((ext_vector_type(16)));
typedef short  s8   __attribute__((ext_vector_type(8)));

#define NPTS   8192
#define NB     4
#define NPTOT  (NB * NPTS)        // 32768 points per cloud
#define NSEG   4                  // column-segment split (2048 cols each)
#define RBLK   128

__device__ __forceinline__ ushort f2bf(float f) {
    uint u = __float_as_uint(f);
    u += 0x7FFF + ((u >> 16) & 1);          // round-to-nearest-even
    return (ushort)(u >> 16);
}
__device__ __forceinline__ float bf2f(ushort h) {
    return __uint_as_float(((uint)h) << 16);
}
__device__ __forceinline__ uint pk(ushort lo, ushort hi) {
    return (uint)lo | ((uint)hi << 16);
}

// prep: per point (both clouds): split coords and ||p||^2 into bf16 hi/lo,
// store A-side records (rows) and B-side records (cols), 2 x uint4 each.
__global__ __launch_bounds__(256) void prep(
        const float* __restrict__ X, const float* __restrict__ Y,
        uint4* __restrict__ Arec, uint4* __restrict__ Brec) {
    int i = blockIdx.x * 256 + threadIdx.x;
    if (i >= 2 * NPTOT) return;
    const float* src = (i < NPTOT) ? X : Y;
    int p = i & (NPTOT - 1);
    float x0 = src[3*p], x1 = src[3*p+1], x2 = src[3*p+2];
    float n2 = __fmaf_rn(x0, x0, __fmaf_rn(x1, x1, x2 * x2));

    ushort h0 = f2bf(x0), h1 = f2bf(x1), h2 = f2bf(x2);
    ushort l0 = f2bf(x0 - bf2f(h0));
    ushort l1 = f2bf(x1 - bf2f(h1));
    ushort l2 = f2bf(x2 - bf2f(h2));
    ushort n2h = f2bf(n2);
    ushort n2l = f2bf(n2 - bf2f(n2h));
    ushort a0 = f2bf(-2.0f * bf2f(h0)), a1 = f2bf(-2.0f * bf2f(h1));
    ushort a2 = f2bf(-2.0f * bf2f(h2));
    ushort b0 = f2bf(-2.0f * bf2f(l0)), b1 = f2bf(-2.0f * bf2f(l1));
    ushort b2 = f2bf(-2.0f * bf2f(l2));
    const ushort ONE = 0x3F80;

    Arec[(size_t)i*2 + 0] = make_uint4(pk(a0,a1), pk(a2,ONE), pk(b0,b1), pk(b2,ONE));
    Arec[(size_t)i*2 + 1] = make_uint4(pk(a0,a1), pk(a2,0),   0,          0);
    Brec[(size_t)i*2 + 0] = make_uint4(pk(h0,h1), pk(h2,n2h), pk(h0,h1), pk(h2,n2l));
    Brec[(size_t)i*2 + 1] = make_uint4(pk(l0,l1), pk(l2,0),   0,          0);
}

// load a pair of adjacent col-tile fragments (16B/lane each, coalesced)
#define LOADP(P, p)                                                        \
    P[0] = *(const s8*)(Bseg + (size_t)(2 * (p)) * 64 + boff);             \
    P[1] = *(const s8*)(Bseg + (size_t)(2 * (p) + 1) * 64 + boff);

// sequenced: at most 2 acc tiles (32 regs) live at any point
#define COMP(P)                                                            \
    {                                                                      \
        f16v a0 = __builtin_amdgcn_mfma_f32_32x32x16_bf16(A0, P[0], zero16, 0, 0, 0); \
        f16v a1 = __builtin_amdgcn_mfma_f32_32x32x16_bf16(A0, P[1], zero16, 0, 0, 0); \
        _Pragma("unroll")                                                  \
        for (int q = 0; q < 16; q++)                                       \
            racc0[q] = fminf(fminf(a0[q], a1[q]), racc0[q]);               \
        f16v b0 = __builtin_amdgcn_mfma_f32_32x32x16_bf16(A1, P[0], zero16, 0, 0, 0); \
        f16v b1 = __builtin_amdgcn_mfma_f32_32x32x16_bf16(A1, P[1], zero16, 0, 0, 0); \
        _Pragma("unroll")                                                  \
        for (int q = 0; q < 16; q++)                                       \
            racc1[q] = fminf(fminf(b0[q], b1[q]), racc1[q]);               \
    }

__global__ __launch_bounds__(256) void mfma_pass(
        const uint4* __restrict__ Arec, const uint4* __restrict__ Brec,
        float* __restrict__ minsP) {
    // grid = 1024: pass(2) x batch(4) x rowblk(32) x seg(4)
    // block = 4 waves; wave owns 64 rows x one 2048-col segment
    int bid    = blockIdx.x;
    int pass   = bid >> 9;
    int r      = bid & 511;
    int b      = r >> 7;
    int rem    = r & 127;
    int rowblk = rem >> 2;
    int seg    = rem & 3;
    int lane   = threadIdx.x & 63;
    int wave   = threadIdx.x >> 6;
    int ca     = pass;              // A-cloud: 0=X,1=Y
    int cb     = 1 - pass;
    int rowbase = rowblk * 256 + wave * 64;

    // two A fragments: rows [rowbase,+32) and [rowbase+32,+64)
    size_t pA = (size_t)ca * NPTOT + (size_t)b * NPTS + rowbase + (lane & 31);
    int krec = lane >> 5;
    s8 A0 = *(const s8*)&Arec[(pA)      * 2 + krec];
    s8 A1 = *(const s8*)&Arec[(pA + 32) * 2 + krec];

    // B segment: 2048 points = 64 col-tiles (64 recs of 16B each)
    const uint4* Bseg = Brec + ((size_t)cb * NPTOT + (size_t)b * NPTS
                      + (size_t)seg * 2048) * 2;
    int boff = (lane & 31) * 2 + krec;

    const f16v zero16 = {0,0,0,0,0,0,0,0,0,0,0,0,0,0,0,0};
    f16v racc0, racc1;
#pragma unroll
    for (int q = 0; q < 16; q++) { racc0[q] = 3.0e38f; racc1[q] = 3.0e38f; }

    // 32 col-tile pairs, ping-pong prefetch (no extra outer unroll)
    s8 PA[2], PB[2];
    LOADP(PA, 0);
#pragma unroll 1
    for (int p = 0; p < 30; p += 2) {
        LOADP(PB, p + 1);
        COMP(PA);
        LOADP(PA, p + 2);
        COMP(PB);
    }
    LOADP(PB, 31);
    COMP(PA);
    COMP(PB);

    // row-min across 32 cols (lane bits 0-4), plain store per segment
    float* dst = minsP + ((size_t)seg * 2 + pass) * NPTOT + (size_t)b * NPTS;
    int half = lane >> 5;
#pragma unroll
    for (int h2 = 0; h2 < 2; h2++) {
#pragma unroll
        for (int q = 0; q < 16; q++) {
            float v = h2 ? racc1[q] : racc0[q];
            v = fminf(v, __shfl_xor(v, 1, 64));
            v = fminf(v, __shfl_xor(v, 2, 64));
            v = fminf(v, __shfl_xor(v, 4, 64));
            v = fminf(v, __shfl_xor(v, 8, 64));
            v = fminf(v, __shfl_xor(v, 16, 64));
            if ((lane & 31) == 0)
                dst[rowbase + h2 * 32 + (q & 3) + 8 * (q >> 2) + 4 * half] = v;
        }
    }
}

__global__ __launch_bounds__(256) void reduce1(
        const float* __restrict__ minsP,
        const float* __restrict__ X, const float* __restrict__ Y,
        float2* __restrict__ out2) {
    __shared__ float s1[256], s2[256];
    int t = threadIdx.x;
    int i = blockIdx.x * 256 + t;           // RBLK*256 == NPTOT exactly
    float mx = 3.0e38f, my = 3.0e38f;
#pragma unroll
    for (int s = 0; s < NSEG; s++) {
        mx = fminf(mx, minsP[((size_t)s * 2 + 0) * NPTOT + i]);
        my = fminf(my, minsP[((size_t)s * 2 + 1) * NPTOT + i]);
    }
    float a = X[3*i], bb = X[3*i+1], c = X[3*i+2];
    float sx = mx + __fmaf_rn(a, a, __fmaf_rn(bb, bb, c * c));
    float d = Y[3*i], e = Y[3*i+1], f = Y[3*i+2];
    float sy = my + __fmaf_rn(d, d, __fmaf_rn(e, e, f * f));
    s1[t] = sx; s2[t] = sy;
    __syncthreads();
    for (int s = 128; s > 0; s >>= 1) {
        if (t < s) { s1[t] += s1[t + s]; s2[t] += s2[t + s]; }
        __syncthreads();
    }
    if (t == 0) out2[blockIdx.x] = make_float2(s1[0], s2[0]);
}

__global__ __launch_bounds__(RBLK) void reduce2(
        const float2* __restrict__ p2,
        const float* __restrict__ bpp, const float* __restrict__ lam,
        float* __restrict__ out) {
    __shared__ float s[RBLK];
    int t = threadIdx.x;
    float2 p = p2[t];
    s[t] = p.x + p.y;
    __syncthreads();
    for (int h = RBLK / 2; h > 0; h >>= 1) {
        if (t < h) s[t] += s[t + h];
        __syncthreads();
    }
    if (t == 0) out[0] = s[0] * (1.0f / (float)NPTOT) + lam[0] * bpp[0];
}

extern "C" void kernel_launch(void* const* d_in, const int* in_sizes, int n_in,
                              void* d_out, int out_size, void* d_ws, size_t ws_size,
                              hipStream_t stream) {
    const float* X   = (const float*)d_in[0];   // pc_pred  [4,8192,3]
    const float* Y   = (const float*)d_in[1];   // pc_target[4,8192,3]
    const float* bpp = (const float*)d_in[2];
    const float* lam = (const float*)d_in[3];
    float* out = (float*)d_out;

    char* w = (char*)d_ws;
    float2* p2    = (float2*)w;                 w += 1024;
    float*  minsP = (float*)w;                  w += (size_t)NSEG * 2 * NPTOT * sizeof(float);
    uint4*  Arec  = (uint4*)w;                  w += (size_t)2 * NPTOT * 2 * sizeof(uint4);
    uint4*  Brec  = (uint4*)w;

    prep<<<(2 * NPTOT + 255) / 256, 256, 0, stream>>>(X, Y, Arec, Brec);
    mfma_pass<<<1024, 256, 0, stream>>>(Arec, Brec, minsP);
    reduce1<<<RBLK, 256, 0, stream>>>(minsP, X, Y, p2);
    reduce2<<<1, RBLK, 0, stream>>>(p2, bpp, lam, out);
}

// Round 12
// 41.400 us; speedup vs baseline: 2.2706x; 1.1494x over previous
//
#include <hip/hip_runtime.h>

// Chamfer loss: B=4, N=M=8192, D=3, fp32 in, scalar fp32 out.
// loss = mean_n min_m ||x_n-y_m||^2 + mean_m min_n ||...||^2 + lambda*bpp
//
// R11 = R6 (verified bit-exact, best total 40.6us) + 2-way column-segment
// split for TLP only. R6 ran 2048 waves (2/SIMD) and its pass (~30us vs
// ~7us pipe budget) is latency-exposure at low occupancy. NSEG=2 doubles
// waves to 4096 (4/SIMD, the VGPR~124 occupancy cap) with identical
// total MFMA/VALU/B-traffic. Inner loop untouched: ONE builtin MFMA and
// one 16-fmin merge live at a time (R7-R9 showed batching MFMAs inflates
// VALU 3-6x via AGPR moves). Partial mins: plain stores, folded in
// reduce1.
// Math: P = y2 - 2 x.y via split-bf16 in K (one 32x32x16 per tile):
//   k0-2: -2xhi*yhi  k3: 1*y2hi  k4-6: -2xlo*yhi  k7: 1*y2lo
//   k8-10: -2xhi*ylo k11-15: 0
// A/B frag: row/col = lane&31, k-octet = lane>>5.
// C/D: col = lane&31, row = (q&3)+8*(q>>2)+4*(lane>>5).

typedef float  f16v __attribute__((ext_vector_type(16)));
typedef short  s8   __attribute__((ext_vector_type(8)));

#define NPTS   8192
#define NB     4
#define NPTOT  (NB * NPTS)        // 32768 points per cloud
#define NSEG   2                  // column-segment split (4096 cols each)
#define RBLK   128

__device__ __forceinline__ ushort f2bf(float f) {
    uint u = __float_as_uint(f);
    u += 0x7FFF + ((u >> 16) & 1);          // round-to-nearest-even
    return (ushort)(u >> 16);
}
__device__ __forceinline__ float bf2f(ushort h) {
    return __uint_as_float(((uint)h) << 16);
}
__device__ __forceinline__ uint pk(ushort lo, ushort hi) {
    return (uint)lo | ((uint)hi << 16);
}

// prep: per point (both clouds): split coords and ||p||^2 into bf16 hi/lo,
// store A-side records (rows) and B-side records (cols), 2 x uint4 each.
__global__ __launch_bounds__(256) void prep(
        const float* __restrict__ X, const float* __restrict__ Y,
        uint4* __restrict__ Arec, uint4* __restrict__ Brec) {
    int i = blockIdx.x * 256 + threadIdx.x;
    if (i >= 2 * NPTOT) return;
    const float* src = (i < NPTOT) ? X : Y;
    int p = i & (NPTOT - 1);
    float x0 = src[3*p], x1 = src[3*p+1], x2 = src[3*p+2];
    float n2 = __fmaf_rn(x0, x0, __fmaf_rn(x1, x1, x2 * x2));

    ushort h0 = f2bf(x0), h1 = f2bf(x1), h2 = f2bf(x2);
    ushort l0 = f2bf(x0 - bf2f(h0));
    ushort l1 = f2bf(x1 - bf2f(h1));
    ushort l2 = f2bf(x2 - bf2f(h2));
    ushort n2h = f2bf(n2);
    ushort n2l = f2bf(n2 - bf2f(n2h));
    ushort a0 = f2bf(-2.0f * bf2f(h0)), a1 = f2bf(-2.0f * bf2f(h1));
    ushort a2 = f2bf(-2.0f * bf2f(h2));
    ushort b0 = f2bf(-2.0f * bf2f(l0)), b1 = f2bf(-2.0f * bf2f(l1));
    ushort b2 = f2bf(-2.0f * bf2f(l2));
    const ushort ONE = 0x3F80;

    Arec[(size_t)i*2 + 0] = make_uint4(pk(a0,a1), pk(a2,ONE), pk(b0,b1), pk(b2,ONE));
    Arec[(size_t)i*2 + 1] = make_uint4(pk(a0,a1), pk(a2,0),   0,          0);
    Brec[(size_t)i*2 + 0] = make_uint4(pk(h0,h1), pk(h2,n2h), pk(h0,h1), pk(h2,n2l));
    Brec[(size_t)i*2 + 1] = make_uint4(pk(l0,l1), pk(l2,0),   0,          0);
}

#define LOADG(G, g)                                                        \
    _Pragma("unroll")                                                      \
    for (int u = 0; u < 4; u++)                                            \
        G[u] = *(const s8*)(Bseg + (size_t)((g) * 4 + u) * 64 + boff);

#define COMPG(G)                                                           \
    _Pragma("unroll")                                                      \
    for (int u = 0; u < 4; u++) {                                          \
        f16v acc = __builtin_amdgcn_mfma_f32_32x32x16_bf16(                \
            afrag, G[u], zero16, 0, 0, 0);                                 \
        _Pragma("unroll")                                                  \
        for (int q = 0; q < 16; q++) racc[q] = fminf(racc[q], acc[q]);     \
    }

__global__ __launch_bounds__(256) void mfma_pass(
        const uint4* __restrict__ Arec, const uint4* __restrict__ Brec,
        float* __restrict__ minsP) {
    // grid = 1024: pass(2) x batch(4) x rowblk(64) x seg(2)
    // block = 4 waves; wave owns 32 rows x one 4096-col segment
    int bid  = blockIdx.x;
    int pass = bid >> 9;            // 0: rows=X cols=Y; 1: rows=Y cols=X
    int r    = bid & 511;
    int b    = r >> 7;
    int rem  = r & 127;
    int blk  = rem >> 1;
    int seg  = rem & 1;
    int lane = threadIdx.x & 63;
    int wave = threadIdx.x >> 6;
    int ca   = pass;                // A-cloud: 0=X,1=Y
    int cb   = 1 - pass;
    int ibase = (blk * 4 + wave) * 32;

    // A fragment: lane&31 = row, lane>>5 = k-half (record index)
    int pA = b * NPTS + ibase + (lane & 31);
    s8 afrag = *(const s8*)&Arec[((size_t)ca * NPTOT + pA) * 2 + (lane >> 5)];

    // B segment: 4096 points = 128 col-tiles (64 recs of 16B each)
    const uint4* Bseg = Brec + ((size_t)cb * NPTOT + (size_t)b * NPTS
                      + (size_t)seg * 4096) * 2;
    int boff = (lane & 31) * 2 + (lane >> 5);   // col = lane&31, rec = lane>>5

    const f16v zero16 = {0,0,0,0,0,0,0,0,0,0,0,0,0,0,0,0};
    f16v racc;
#pragma unroll
    for (int q = 0; q < 16; q++) racc[q] = 3.0e38f;

    // 32 groups of 4 col-tiles, ping-pong prefetch
    s8 GA[4], GB[4];
    LOADG(GA, 0);
    for (int g = 0; g < 30; g += 2) {
        LOADG(GB, g + 1);
        COMPG(GA);
        LOADG(GA, g + 2);
        COMPG(GB);
    }
    LOADG(GB, 31);
    COMPG(GA);
    COMPG(GB);

    // row-min across the 32 cols (lane bits 0-4), rows stay fixed
#pragma unroll
    for (int q = 0; q < 16; q++) {
        float v = racc[q];
        v = fminf(v, __shfl_xor(v, 1, 64));
        v = fminf(v, __shfl_xor(v, 2, 64));
        v = fminf(v, __shfl_xor(v, 4, 64));
        v = fminf(v, __shfl_xor(v, 8, 64));
        v = fminf(v, __shfl_xor(v, 16, 64));
        racc[q] = v;
    }
    if ((lane & 31) == 0) {
        float* dst = minsP + ((size_t)seg * 2 + pass) * NPTOT
                   + (size_t)b * NPTS + ibase;
        int half = lane >> 5;       // row offset +4 for lanes 32..63
#pragma unroll
        for (int q = 0; q < 16; q++)
            dst[(q & 3) + 8 * (q >> 2) + 4 * half] = racc[q];
    }
}

__global__ __launch_bounds__(256) void reduce1(
        const float* __restrict__ minsP,
        const float* __restrict__ X, const float* __restrict__ Y,
        float2* __restrict__ out2) {
    __shared__ float s1[256], s2[256];
    int t = threadIdx.x;
    int i = blockIdx.x * 256 + t;           // RBLK*256 == NPTOT exactly
    float mx = 3.0e38f, my = 3.0e38f;
#pragma unroll
    for (int s = 0; s < NSEG; s++) {
        mx = fminf(mx, minsP[((size_t)s * 2 + 0) * NPTOT + i]);
        my = fminf(my, minsP[((size_t)s * 2 + 1) * NPTOT + i]);
    }
    float a = X[3*i], bb = X[3*i+1], c = X[3*i+2];
    float sx = mx + __fmaf_rn(a, a, __fmaf_rn(bb, bb, c * c));
    float d = Y[3*i], e = Y[3*i+1], f = Y[3*i+2];
    float sy = my + __fmaf_rn(d, d, __fmaf_rn(e, e, f * f));
    s1[t] = sx; s2[t] = sy;
    __syncthreads();
    for (int s = 128; s > 0; s >>= 1) {
        if (t < s) { s1[t] += s1[t + s]; s2[t] += s2[t + s]; }
        __syncthreads();
    }
    if (t == 0) out2[blockIdx.x] = make_float2(s1[0], s2[0]);
}

__global__ __launch_bounds__(RBLK) void reduce2(
        const float2* __restrict__ p2,
        const float* __restrict__ bpp, const float* __restrict__ lam,
        float* __restrict__ out) {
    __shared__ float s[RBLK];
    int t = threadIdx.x;
    float2 p = p2[t];
    s[t] = p.x + p.y;
    __syncthreads();
    for (int h = RBLK / 2; h > 0; h >>= 1) {
        if (t < h) s[t] += s[t + h];
        __syncthreads();
    }
    if (t == 0) out[0] = s[0] * (1.0f / (float)NPTOT) + lam[0] * bpp[0];
}

extern "C" void kernel_launch(void* const* d_in, const int* in_sizes, int n_in,
                              void* d_out, int out_size, void* d_ws, size_t ws_size,
                              hipStream_t stream) {
    const float* X   = (const float*)d_in[0];   // pc_pred  [4,8192,3]
    const float* Y   = (const float*)d_in[1];   // pc_target[4,8192,3]
    const float* bpp = (const float*)d_in[2];
    const float* lam = (const float*)d_in[3];
    float* out = (float*)d_out;

    char* w = (char*)d_ws;
    float2* p2    = (float2*)w;                 w += 1024;
    float*  minsP = (float*)w;                  w += (size_t)NSEG * 2 * NPTOT * sizeof(float);
    uint4*  Arec  = (uint4*)w;                  w += (size_t)2 * NPTOT * 2 * sizeof(uint4);
    uint4*  Brec  = (uint4*)w;

    prep<<<(2 * NPTOT + 255) / 256, 256, 0, stream>>>(X, Y, Arec, Brec);
    mfma_pass<<<1024, 256, 0, stream>>>(Arec, Brec, minsP);
    reduce1<<<RBLK, 256, 0, stream>>>(minsP, X, Y, p2);
    reduce2<<<1, RBLK, 0, stream>>>(p2, bpp, lam, out);
}

// Round 13
// 40.556 us; speedup vs baseline: 2.3179x; 1.0208x over previous
//
#include <hip/hip_runtime.h>

// Chamfer loss: B=4, N=M=8192, D=3, fp32 in, scalar fp32 out.
// loss = mean_n min_m ||x_n-y_m||^2 + mean_m min_n ||...||^2 + lambda*bpp
//
// R12 = R11 (verified, 41.4us) with ONE controlled change: the per-tile
// merge uses paired v_min3 (16 min3 per 2 col-tiles) instead of 16 fmin
// per tile -> merge VALU halves. Max 2 acc tiles (32 regs) live, single
// A-frag (R9's failure had 2 A-frags x 2 tiles = 4 accs in scheduler
// range; this is the uncontaminated test of merge-VALU inflation).
// Everything else identical to R11: NSEG=2, grid 1024, 4 waves/block,
// wave owns 32 rows x 4096-col segment.
// Math (bit-exact since R6): P = y2 - 2 x.y via one 32x32x16 per tile:
//   k0-2: -2xhi*yhi  k3: 1*y2hi  k4-6: -2xlo*yhi  k7: 1*y2lo
//   k8-10: -2xhi*ylo k11-15: 0
// A/B frag: row/col = lane&31, k-octet = lane>>5.
// C/D: col = lane&31, row = (q&3)+8*(q>>2)+4*(lane>>5).

typedef float  f16v __attribute__((ext_vector_type(16)));
typedef short  s8   __attribute__((ext_vector_type(8)));

#define NPTS   8192
#define NB     4
#define NPTOT  (NB * NPTS)        // 32768 points per cloud
#define NSEG   2                  // column-segment split (4096 cols each)
#define RBLK   128

__device__ __forceinline__ ushort f2bf(float f) {
    uint u = __float_as_uint(f);
    u += 0x7FFF + ((u >> 16) & 1);          // round-to-nearest-even
    return (ushort)(u >> 16);
}
__device__ __forceinline__ float bf2f(ushort h) {
    return __uint_as_float(((uint)h) << 16);
}
__device__ __forceinline__ uint pk(ushort lo, ushort hi) {
    return (uint)lo | ((uint)hi << 16);
}

// prep: per point (both clouds): split coords and ||p||^2 into bf16 hi/lo,
// store A-side records (rows) and B-side records (cols), 2 x uint4 each.
__global__ __launch_bounds__(256) void prep(
        const float* __restrict__ X, const float* __restrict__ Y,
        uint4* __restrict__ Arec, uint4* __restrict__ Brec) {
    int i = blockIdx.x * 256 + threadIdx.x;
    if (i >= 2 * NPTOT) return;
    const float* src = (i < NPTOT) ? X : Y;
    int p = i & (NPTOT - 1);
    float x0 = src[3*p], x1 = src[3*p+1], x2 = src[3*p+2];
    float n2 = __fmaf_rn(x0, x0, __fmaf_rn(x1, x1, x2 * x2));

    ushort h0 = f2bf(x0), h1 = f2bf(x1), h2 = f2bf(x2);
    ushort l0 = f2bf(x0 - bf2f(h0));
    ushort l1 = f2bf(x1 - bf2f(h1));
    ushort l2 = f2bf(x2 - bf2f(h2));
    ushort n2h = f2bf(n2);
    ushort n2l = f2bf(n2 - bf2f(n2h));
    ushort a0 = f2bf(-2.0f * bf2f(h0)), a1 = f2bf(-2.0f * bf2f(h1));
    ushort a2 = f2bf(-2.0f * bf2f(h2));
    ushort b0 = f2bf(-2.0f * bf2f(l0)), b1 = f2bf(-2.0f * bf2f(l1));
    ushort b2 = f2bf(-2.0f * bf2f(l2));
    const ushort ONE = 0x3F80;

    Arec[(size_t)i*2 + 0] = make_uint4(pk(a0,a1), pk(a2,ONE), pk(b0,b1), pk(b2,ONE));
    Arec[(size_t)i*2 + 1] = make_uint4(pk(a0,a1), pk(a2,0),   0,          0);
    Brec[(size_t)i*2 + 0] = make_uint4(pk(h0,h1), pk(h2,n2h), pk(h0,h1), pk(h2,n2l));
    Brec[(size_t)i*2 + 1] = make_uint4(pk(l0,l1), pk(l2,0),   0,          0);
}

#define LOADG(G, g)                                                        \
    _Pragma("unroll")                                                      \
    for (int u = 0; u < 4; u++)                                            \
        G[u] = *(const s8*)(Bseg + (size_t)((g) * 4 + u) * 64 + boff);

// paired merge: 2 MFMAs then 16 min3 (2 acc tiles live, 32 regs max)
#define COMPG(G)                                                           \
    _Pragma("unroll")                                                      \
    for (int u = 0; u < 4; u += 2) {                                       \
        f16v acc0 = __builtin_amdgcn_mfma_f32_32x32x16_bf16(               \
            afrag, G[u], zero16, 0, 0, 0);                                 \
        f16v acc1 = __builtin_amdgcn_mfma_f32_32x32x16_bf16(               \
            afrag, G[u + 1], zero16, 0, 0, 0);                             \
        _Pragma("unroll")                                                  \
        for (int q = 0; q < 16; q++)                                       \
            racc[q] = fminf(fminf(acc0[q], acc1[q]), racc[q]);             \
    }

__global__ __launch_bounds__(256) void mfma_pass(
        const uint4* __restrict__ Arec, const uint4* __restrict__ Brec,
        float* __restrict__ minsP) {
    // grid = 1024: pass(2) x batch(4) x rowblk(64) x seg(2)
    // block = 4 waves; wave owns 32 rows x one 4096-col segment
    int bid  = blockIdx.x;
    int pass = bid >> 9;            // 0: rows=X cols=Y; 1: rows=Y cols=X
    int r    = bid & 511;
    int b    = r >> 7;
    int rem  = r & 127;
    int blk  = rem >> 1;
    int seg  = rem & 1;
    int lane = threadIdx.x & 63;
    int wave = threadIdx.x >> 6;
    int ca   = pass;                // A-cloud: 0=X,1=Y
    int cb   = 1 - pass;
    int ibase = (blk * 4 + wave) * 32;

    // A fragment: lane&31 = row, lane>>5 = k-half (record index)
    int pA = b * NPTS + ibase + (lane & 31);
    s8 afrag = *(const s8*)&Arec[((size_t)ca * NPTOT + pA) * 2 + (lane >> 5)];

    // B segment: 4096 points = 128 col-tiles (64 recs of 16B each)
    const uint4* Bseg = Brec + ((size_t)cb * NPTOT + (size_t)b * NPTS
                      + (size_t)seg * 4096) * 2;
    int boff = (lane & 31) * 2 + (lane >> 5);   // col = lane&31, rec = lane>>5

    const f16v zero16 = {0,0,0,0,0,0,0,0,0,0,0,0,0,0,0,0};
    f16v racc;
#pragma unroll
    for (int q = 0; q < 16; q++) racc[q] = 3.0e38f;

    // 32 groups of 4 col-tiles, ping-pong prefetch
    s8 GA[4], GB[4];
    LOADG(GA, 0);
    for (int g = 0; g < 30; g += 2) {
        LOADG(GB, g + 1);
        COMPG(GA);
        LOADG(GA, g + 2);
        COMPG(GB);
    }
    LOADG(GB, 31);
    COMPG(GA);
    COMPG(GB);

    // row-min across the 32 cols (lane bits 0-4), rows stay fixed
#pragma unroll
    for (int q = 0; q < 16; q++) {
        float v = racc[q];
        v = fminf(v, __shfl_xor(v, 1, 64));
        v = fminf(v, __shfl_xor(v, 2, 64));
        v = fminf(v, __shfl_xor(v, 4, 64));
        v = fminf(v, __shfl_xor(v, 8, 64));
        v = fminf(v, __shfl_xor(v, 16, 64));
        racc[q] = v;
    }
    if ((lane & 31) == 0) {
        float* dst = minsP + ((size_t)seg * 2 + pass) * NPTOT
                   + (size_t)b * NPTS + ibase;
        int half = lane >> 5;       // row offset +4 for lanes 32..63
#pragma unroll
        for (int q = 0; q < 16; q++)
            dst[(q & 3) + 8 * (q >> 2) + 4 * half] = racc[q];
    }
}

__global__ __launch_bounds__(256) void reduce1(
        const float* __restrict__ minsP,
        const float* __restrict__ X, const float* __restrict__ Y,
        float2* __restrict__ out2) {
    __shared__ float s1[256], s2[256];
    int t = threadIdx.x;
    int i = blockIdx.x * 256 + t;           // RBLK*256 == NPTOT exactly
    float mx = 3.0e38f, my = 3.0e38f;
#pragma unroll
    for (int s = 0; s < NSEG; s++) {
        mx = fminf(mx, minsP[((size_t)s * 2 + 0) * NPTOT + i]);
        my = fminf(my, minsP[((size_t)s * 2 + 1) * NPTOT + i]);
    }
    float a = X[3*i], bb = X[3*i+1], c = X[3*i+2];
    float sx = mx + __fmaf_rn(a, a, __fmaf_rn(bb, bb, c * c));
    float d = Y[3*i], e = Y[3*i+1], f = Y[3*i+2];
    float sy = my + __fmaf_rn(d, d, __fmaf_rn(e, e, f * f));
    s1[t] = sx; s2[t] = sy;
    __syncthreads();
    for (int s = 128; s > 0; s >>= 1) {
        if (t < s) { s1[t] += s1[t + s]; s2[t] += s2[t + s]; }
        __syncthreads();
    }
    if (t == 0) out2[blockIdx.x] = make_float2(s1[0], s2[0]);
}

__global__ __launch_bounds__(RBLK) void reduce2(
        const float2* __restrict__ p2,
        const float* __restrict__ bpp, const float* __restrict__ lam,
        float* __restrict__ out) {
    __shared__ float s[RBLK];
    int t = threadIdx.x;
    float2 p = p2[t];
    s[t] = p.x + p.y;
    __syncthreads();
    for (int h = RBLK / 2; h > 0; h >>= 1) {
        if (t < h) s[t] += s[t + h];
        __syncthreads();
    }
    if (t == 0) out[0] = s[0] * (1.0f / (float)NPTOT) + lam[0] * bpp[0];
}

extern "C" void kernel_launch(void* const* d_in, const int* in_sizes, int n_in,
                              void* d_out, int out_size, void* d_ws, size_t ws_size,
                              hipStream_t stream) {
    const float* X   = (const float*)d_in[0];   // pc_pred  [4,8192,3]
    const float* Y   = (const float*)d_in[1];   // pc_target[4,8192,3]
    const float* bpp = (const float*)d_in[2];
    const float* lam = (const float*)d_in[3];
    float* out = (float*)d_out;

    char* w = (char*)d_ws;
    float2* p2    = (float2*)w;                 w += 1024;
    float*  minsP = (float*)w;                  w += (size_t)NSEG * 2 * NPTOT * sizeof(float);
    uint4*  Arec  = (uint4*)w;                  w += (size_t)2 * NPTOT * 2 * sizeof(uint4);
    uint4*  Brec  = (uint4*)w;

    prep<<<(2 * NPTOT + 255) / 256, 256, 0, stream>>>(X, Y, Arec, Brec);
    mfma_pass<<<1024, 256, 0, stream>>>(Arec, Brec, minsP);
    reduce1<<<RBLK, 256, 0, stream>>>(minsP, X, Y, p2);
    reduce2<<<1, RBLK, 0, stream>>>(p2, bpp, lam, out);
}